// Round 8
// baseline (351.306 us; speedup 1.0000x reference)
//
#include <hip/hip_runtime.h>

#define NN 20000
#define NE 320000
#define NG 256
#define NZ 728            // 7*104
#define NH 104            // 64+24+16
#define NCOMP 216         // 64 + 24*3 + 16*5

static __device__ __forceinline__ float bf2f(unsigned short u) {
    unsigned int x = ((unsigned int)u) << 16;
    union { unsigned int i; float f; } c; c.i = x; return c.f;
}
static __device__ __forceinline__ unsigned short f2bf(float f) {
    union { float f; unsigned int i; } c; c.f = f;
    unsigned int x = c.i;
    return (unsigned short)((x + 0x7FFFu + ((x >> 16) & 1u)) >> 16);
}

// ---------------- K1: blocks [0,1250) count degrees; rest build Wz (24 rows, row23=0) ----------------

__global__ __launch_bounds__(256) void k_count_wz(const int* __restrict__ esrc,
                                                  const int* __restrict__ edst,
                                                  const float* __restrict__ W1,
                                                  const float* __restrict__ W2,
                                                  const float* __restrict__ W3,
                                                  int* __restrict__ deg_src,
                                                  int* __restrict__ deg_dst,
                                                  float* __restrict__ Wz)
{
    const int b = blockIdx.x, t = threadIdx.x;
    if (b < 1250) {
        const int e = b * 256 + t;           // 1250*256 == NE exactly
        atomicAdd(&deg_src[esrc[e]], 1);
        atomicAdd(&deg_dst[edst[e]], 1);
    } else {
        const int idx = (b - 1250) * 256 + t;   // Wz: [u][v*104+w], a1 folded
        if (idx < 24 * NZ) {
            const int u = idx / NZ, c = idx - u * NZ;
            const int v = c / NH, w = c - v * NH;
            float val = 0.f;
            if (u < 23) {
                if (w < 64)      val = W1[(u*7 + v)*64 + w];
                else if (w < 88) val = W2[(u*7 + v)*24 + (w - 64)];
                else             val = W3[(u*7 + v)*16 + (w - 88)];
                val *= 0.07881104f;          // a1 = 1/sqrt(23*7)
            }
            Wz[idx] = val;
        }
    }
}

// ---------------- K2: blocks 0,1 scan degrees (shuffle scan); blocks 2.. node_z ----------------

__global__ __launch_bounds__(256) void k_scan_nodez(const int* __restrict__ deg_src,
                                                    const int* __restrict__ deg_dst,
                                                    const float* __restrict__ x,
                                                    const float* __restrict__ Wz,
                                                    int* __restrict__ offs_src,
                                                    int* __restrict__ cur_src,
                                                    int* __restrict__ offs_dst,
                                                    int* __restrict__ cur_dst,
                                                    float* __restrict__ z)
{
    __shared__ __align__(16) char smem[1024];
    const int b = blockIdx.x, t = threadIdx.x;
    if (b < 2) {
        int* wsum = (int*)smem;                 // [4]
        const int* deg = b ? deg_dst : deg_src;
        int* offs = b ? offs_dst : offs_src;
        int* cur  = b ? cur_dst  : cur_src;
        const int lane = t & 63, wid = t >> 6;
        const int NCH = 79;                     // 79*256 >= 20000
        int run = 0;
        int nextv = (t < NN) ? deg[t] : 0;
        for (int c = 0; c < NCH; ++c) {
            const int j = c * 256 + t;
            const int v = nextv;
            const int jn = j + 256;
            nextv = (c + 1 < NCH && jn < NN) ? deg[jn] : 0;   // prefetch
            int inc = v;
#pragma unroll
            for (int off = 1; off < 64; off <<= 1) {
                const int o = __shfl_up(inc, off, 64);
                if (lane >= off) inc += o;
            }
            if (lane == 63) wsum[wid] = inc;
            __syncthreads();
            int wbase = 0;
#pragma unroll
            for (int wv = 0; wv < 4; ++wv) if (wv < wid) wbase += wsum[wv];
            const int excl = run + wbase + inc - v;
            if (j < NN) { offs[j] = excl; cur[j] = excl; }
            run += wsum[0] + wsum[1] + wsum[2] + wsum[3];
            __syncthreads();
        }
        if (t == 255) offs[NN] = run;
    } else {
        float (*xa)[24] = (float (*)[24])smem;
        const int base = (b - 2) * 8;
        if (t < 192) {
            const int nl = t / 24, u = t - nl * 24;
            xa[nl][u] = (u < 23) ? x[(size_t)(base + nl) * 23 + u] : 0.f;
        }
        __syncthreads();
        const int c0 = t, c1 = t + 256, c2 = t + 512;
        const bool has2 = (c2 < NZ);
        float acc[8][3];
#pragma unroll
        for (int n = 0; n < 8; ++n) { acc[n][0] = 0.f; acc[n][1] = 0.f; acc[n][2] = 0.f; }
#pragma unroll
        for (int u4 = 0; u4 < 24; u4 += 4) {
            float w[4][3];
#pragma unroll
            for (int k = 0; k < 4; ++k) {
                const float* wr = Wz + (u4 + k) * NZ;
                w[k][0] = wr[c0];
                w[k][1] = wr[c1];
                w[k][2] = has2 ? wr[c2] : 0.f;
            }
#pragma unroll
            for (int n = 0; n < 8; ++n) {
                const float4 xv = *(const float4*)&xa[n][u4];
                acc[n][0] += xv.x*w[0][0] + xv.y*w[1][0] + xv.z*w[2][0] + xv.w*w[3][0];
                acc[n][1] += xv.x*w[0][1] + xv.y*w[1][1] + xv.z*w[2][1] + xv.w*w[3][1];
                acc[n][2] += xv.x*w[0][2] + xv.y*w[1][2] + xv.z*w[2][2] + xv.w*w[3][2];
            }
        }
#pragma unroll
        for (int n = 0; n < 8; ++n) {
            float* zo = z + (size_t)(base + n) * NZ;
            zo[c0] = acc[n][0];
            zo[c1] = acc[n][1];
            if (has2) zo[c2] = acc[n][2];
        }
    }
}

// ---------------- K3: fill dual CSR; pre-gather ea (stride 8) and sh (dst order) ----------------

__global__ __launch_bounds__(256) void k_fill(const float* __restrict__ pos,
                                              const float* __restrict__ eag,
                                              const int* __restrict__ esrc,
                                              const int* __restrict__ edst,
                                              int* __restrict__ cur_src,
                                              int* __restrict__ cur_dst,
                                              int* __restrict__ srcq,
                                              int* __restrict__ pq,
                                              float* __restrict__ eaq,
                                              float* __restrict__ shq)
{
    const int e = blockIdx.x * 256 + threadIdx.x;   // grid = 1250 exact
    const int s = esrc[e], d = edst[e];
    const int q = atomicAdd(&cur_src[s], 1);
    const int p = atomicAdd(&cur_dst[d], 1);
    srcq[q] = s;
    pq[q] = p;
    float* o = eaq + (size_t)q * 8;
#pragma unroll
    for (int v = 0; v < 7; ++v) o[v] = eag[(size_t)e * 7 + v];
    o[7] = 0.f;
    const float px = pos[3*s+0] - pos[3*d+0];
    const float py = pos[3*s+1] - pos[3*d+1];
    const float pz = pos[3*s+2] - pos[3*d+2];
    const float r2 = px*px + py*py + pz*pz;
    float* sh = shq + (size_t)p * 8;
    sh[0] = 1.7320508f*px;
    sh[1] = 1.7320508f*py;
    sh[2] = 1.7320508f*pz;
    sh[3] = 3.8729833f*px*py;
    sh[4] = 3.8729833f*py*pz;
    sh[5] = 1.1180340f*(3.f*pz*pz - r2);
    sh[6] = 3.8729833f*px*pz;
    sh[7] = 1.9364917f*(px*px - py*py);
}

// ---------------- K4: per-edge h; packed dword stores (comp c & c+52 per lane) ----------------

__global__ __launch_bounds__(256) void k_edge_hb(const float* __restrict__ z,
                                                 const int* __restrict__ offs_src,
                                                 const int* __restrict__ srcq,
                                                 const int* __restrict__ pq,
                                                 const float* __restrict__ eaq,
                                                 unsigned int* __restrict__ hbuf)
{
    __shared__ float zl[8 * NZ];   // 23296 B
    const int t = threadIdx.x;
    const int base = blockIdx.x * 8;
    const float4* zg = (const float4*)(z + (size_t)base * NZ);
    float4* zl4 = (float4*)zl;
    for (int i = t; i < (8 * NZ) / 4; i += 256) zl4[i] = zg[i];
    const int qbeg = offs_src[base], qend = offs_src[base + 8];
    __syncthreads();

    const int lane = t & 63, wid = t >> 6;
    int q = qbeg + wid;
    if (q >= qend) return;
    int slot = srcq[q] - base;
    int p = pq[q];
    float4 eA = ((const float4*)(eaq + (size_t)q * 8))[0];
    float4 eB = ((const float4*)(eaq + (size_t)q * 8))[1];

    while (1) {
        const int qn = q + 4;
        const bool more = qn < qend;
        int slotn = 0, pn = 0;
        float4 eAn = eA, eBn = eB;
        if (more) {
            slotn = srcq[qn] - base;
            pn = pq[qn];
            eAn = ((const float4*)(eaq + (size_t)qn * 8))[0];
            eBn = ((const float4*)(eaq + (size_t)qn * 8))[1];
        }
        if (lane < 52) {
            const float* zr = zl + slot * NZ + lane;
            const float ha = eA.x*zr[0]   + eA.y*zr[104] + eA.z*zr[208]
                           + eA.w*zr[312] + eB.x*zr[416] + eB.y*zr[520] + eB.z*zr[624];
            const float hb = eA.x*zr[52]  + eA.y*zr[156] + eA.z*zr[260]
                           + eA.w*zr[364] + eB.x*zr[468] + eB.y*zr[572] + eB.z*zr[676];
            // dword d holds comps d (low) and d+52 (high)
            hbuf[(size_t)p * 52 + lane] = ((unsigned int)f2bf(hb) << 16) | (unsigned int)f2bf(ha);
        }
        if (!more) break;
        slot = slotn; p = pn; eA = eAn; eB = eBn; q = qn;
    }
}

// ---------------- K5: segment-sum by dst (16-row chunks) + fused V-contraction -> rtab ----------------
// rtab row (64 fp32): [c0*r0[v] (7) | c1*r1[m*7+v] (21) | c2*r2[m*7+v] (35) | pad]

__global__ __launch_bounds__(256) void k_segsum(const unsigned int* __restrict__ hbuf,
                                                const float* __restrict__ shq,
                                                const int* __restrict__ offs_dst,
                                                const float* __restrict__ V1,
                                                const float* __restrict__ V2,
                                                const float* __restrict__ V3,
                                                float* __restrict__ rtab)
{
    const int node = blockIdx.x;
    const int t = threadIdx.x;
    __shared__ uint4 rows4[16][13];   // 16 rows x 52 dwords
    __shared__ float shl[16][8];
    __shared__ float ncl[NCOMP];

    const int beg = offs_dst[node], end = offs_dst[node + 1];

    int kind, wi = 0, mi = 0, comp = 0;
    if (t < 64) { kind = 0; comp = t; }
    else if (t < 136) { const int idx = t - 64;  wi = idx / 3; mi = idx - 3*wi; kind = 1; comp = 64 + wi; }
    else if (t < 216) { const int idx = t - 136; wi = idx / 5; mi = idx - 5*wi; kind = 2; comp = 88 + wi; }
    else kind = 3;
    const int ci = (comp < 52) ? 2*comp : 2*comp - 103;   // ushort index in packed row

    float acc = 0.f;
    const uint4* hb4 = (const uint4*)hbuf;
    for (int j = beg; j < end; j += 16) {
        const int cnt = min(16, end - j);
        __syncthreads();
        if (t < 13 * cnt) {
            const int r = t / 13, c = t - 13 * r;
            rows4[r][c] = hb4[(size_t)(j + r) * 13 + c];
        } else if (t >= 208 && t < 208 + 2 * cnt) {
            const int i = t - 208, r = i >> 1, half = i & 1;
            ((uint4*)&shl[r][0])[half] = ((const uint4*)(shq + (size_t)(j + r) * 8))[half];
        }
        __syncthreads();
        for (int r = 0; r < cnt; ++r) {
            const unsigned short* row = (const unsigned short*)rows4[r];
            if (kind == 0)      acc += bf2f(row[ci]);
            else if (kind == 1) acc += bf2f(row[ci]) * shl[r][mi];
            else if (kind == 2) acc += bf2f(row[ci]) * shl[r][3 + mi];
        }
    }
    if (kind != 3) ncl[t] = acc;
    __syncthreads();

    if (t < 64) {
        float rv = 0.f;
        if (t < 7) {
            const int v = t;
#pragma unroll
            for (int u = 0; u < 64; ++u) rv += ncl[u] * V1[u*7 + v];
            rv *= 0.04724556f;                    // 1/sqrt(64*7)
        } else if (t < 28) {
            const int i = t - 7, m = i / 7, v = i - 7*m;
#pragma unroll
            for (int u = 0; u < 24; ++u) rv += ncl[64 + u*3 + m] * V2[u*7 + v];
            rv *= 0.04454354f;                    // 1/sqrt(24*7*3)
        } else if (t < 63) {
            const int i = t - 28, m = i / 7, v = i - 7*m;
#pragma unroll
            for (int u = 0; u < 16; ++u) rv += ncl[136 + u*5 + m] * V3[u*7 + v];
            rv *= 0.04225771f;                    // 1/sqrt(16*7*5)
        }
        rtab[(size_t)node * 64 + t] = rv;
    }
}

// ---------------- K6: per-edge g via rtab; scatter to 16-way partial bins ----------------

__global__ __launch_bounds__(256) void k_gfinal(const float* __restrict__ pos,
                                                const float* __restrict__ eag,
                                                const int* __restrict__ esrc,
                                                const int* __restrict__ edst,
                                                const int* __restrict__ batch,
                                                const float* __restrict__ rtab,
                                                float* __restrict__ partial)
{
    const int e = blockIdx.x * 256 + threadIdx.x;   // grid = 1250 exact
    const int s = esrc[e], d = edst[e];
    float ea[7];
#pragma unroll
    for (int v = 0; v < 7; ++v) ea[v] = eag[(size_t)e * 7 + v];
    const float px = pos[3*s+0] - pos[3*d+0];
    const float py = pos[3*s+1] - pos[3*d+1];
    const float pz = pos[3*s+2] - pos[3*d+2];
    const float r2 = px*px + py*py + pz*pz;
    const float s10 = 1.7320508f*px, s11 = 1.7320508f*py, s12 = 1.7320508f*pz;
    const float s20 = 3.8729833f*px*py, s21 = 3.8729833f*py*pz,
                s22 = 1.1180340f*(3.f*pz*pz - r2), s23 = 3.8729833f*px*pz,
                s24 = 1.9364917f*(px*px - py*py);

    float rb[64];
    const float4* rr = (const float4*)(rtab + (size_t)s * 64);
#pragma unroll
    for (int i = 0; i < 16; ++i) *(float4*)&rb[4*i] = rr[i];

    float g = 0.f;
#pragma unroll
    for (int v = 0; v < 7; ++v) {
        const float tv = rb[v]
                       + s10*rb[7+v]  + s11*rb[14+v] + s12*rb[21+v]
                       + s20*rb[28+v] + s21*rb[35+v] + s22*rb[42+v]
                       + s23*rb[49+v] + s24*rb[56+v];
        g += ea[v] * tv;
    }
    unsafeAtomicAdd(&partial[(e & 15) * NG + batch[d]], g);
}

// ---------------- K7: reduce 16 partial rows -> out ----------------

__global__ __launch_bounds__(256) void k_reduce(const float* __restrict__ partial,
                                                float* __restrict__ out)
{
    const int gidx = threadIdx.x;
    float s = 0.f;
#pragma unroll
    for (int i = 0; i < 16; ++i) s += partial[i * NG + gidx];
    out[gidx] = s;
}

extern "C" void kernel_launch(void* const* d_in, const int* in_sizes, int n_in,
                              void* d_out, int out_size, void* d_ws, size_t ws_size,
                              hipStream_t stream)
{
    const float* pos  = (const float*)d_in[0];
    const float* x    = (const float*)d_in[1];
    const float* eag  = (const float*)d_in[2];
    const int*   eidx = (const int*)d_in[3];
    const int*   batch= (const int*)d_in[4];
    const float* W1   = (const float*)d_in[5];
    const float* W2   = (const float*)d_in[6];
    const float* W3   = (const float*)d_in[7];
    const float* V1   = (const float*)d_in[8];
    const float* V2   = (const float*)d_in[9];
    const float* V3   = (const float*)d_in[10];
    const int* esrc = eidx;
    const int* edst = eidx + NE;

    char* ws = (char*)d_ws;
    size_t off = 0;
    auto alloc = [&](size_t bytes) -> void* {
        void* p = ws + off;
        off = (off + bytes + 255) & ~(size_t)255;
        return p;
    };
    float* z        = (float*)alloc((size_t)NN * NZ * sizeof(float));        // 58.2 MB
    unsigned int* hbuf = (unsigned int*)alloc((size_t)NE * 52 * sizeof(unsigned int)); // 66.6 MB
    float* shq      = (float*)alloc((size_t)NE * 8 * sizeof(float));         // 10.2 MB
    float* eaq      = (float*)alloc((size_t)NE * 8 * sizeof(float));         // 10.2 MB
    float* rtab     = (float*)alloc((size_t)NN * 64 * sizeof(float));        // 5.1 MB
    int*   srcq     = (int*)alloc((size_t)NE * sizeof(int));
    int*   pq       = (int*)alloc((size_t)NE * sizeof(int));
    float* Wz       = (float*)alloc((size_t)24 * NZ * sizeof(float));
    int*   deg_src  = (int*)alloc((size_t)NN * sizeof(int));     // ---- zeroed region start
    int*   deg_dst  = (int*)alloc((size_t)NN * sizeof(int));
    float* partial  = (float*)alloc((size_t)16 * NG * sizeof(float));
    int*   offs_src = (int*)alloc((size_t)(NN + 1) * sizeof(int));  // ---- zeroed region end
    int*   offs_dst = (int*)alloc((size_t)(NN + 1) * sizeof(int));
    int*   cur_src  = (int*)alloc((size_t)NN * sizeof(int));
    int*   cur_dst  = (int*)alloc((size_t)NN * sizeof(int));

    hipMemsetAsync(deg_src, 0, (size_t)((char*)offs_src - (char*)deg_src), stream);

    k_count_wz<<<1250 + 69, 256, 0, stream>>>(esrc, edst, W1, W2, W3,
                                              deg_src, deg_dst, Wz);
    k_scan_nodez<<<2 + 2500, 256, 0, stream>>>(deg_src, deg_dst, x, Wz,
                                               offs_src, cur_src, offs_dst, cur_dst, z);
    k_fill<<<1250, 256, 0, stream>>>(pos, eag, esrc, edst, cur_src, cur_dst,
                                     srcq, pq, eaq, shq);
    k_edge_hb<<<NN/8, 256, 0, stream>>>(z, offs_src, srcq, pq, eaq, hbuf);
    k_segsum<<<NN, 256, 0, stream>>>(hbuf, shq, offs_dst, V1, V2, V3, rtab);
    k_gfinal<<<1250, 256, 0, stream>>>(pos, eag, esrc, edst, batch, rtab, partial);
    k_reduce<<<1, 256, 0, stream>>>(partial, (float*)d_out);
}